// Round 1
// baseline (176797.119 us; speedup 1.0000x reference)
//
#include <hip/hip_runtime.h>
#include <math.h>
#include <stddef.h>

#define B   32
#define TE  400
#define TD  800
#define ED  512
#define DD  80
#define LS  1024
#define G4  4096
#define UN  128
#define FLT 32
#define KW  31

#define NBLK 256
#define NTHR 512

__device__ __forceinline__ float fsig(float x){ return 1.f/(1.f+__expf(-x)); }
__device__ __forceinline__ float ftanh(float x){ return 1.f - 2.f/(__expf(2.f*x)+1.f); }

// ---------------- keys = values @ Wm : [B, TE, UN] (one-time) ----------------
__global__ void keys_kernel(const float* __restrict__ values, const float* __restrict__ Wm,
                            float* __restrict__ keys)
{
    int b  = blockIdx.x;      // 0..31
    int tg = blockIdx.y;      // 0..49 (groups of 8 t_enc rows)
    int tid = threadIdx.x;    // 128
    __shared__ __align__(16) float v[8*512];
    const float* vb = values + (size_t)b*TE*ED + (size_t)tg*8*ED;
    for (int i = tid; i < 8*512; i += 128) v[i] = vb[i];
    __syncthreads();
    int u = tid;
    float acc[8];
#pragma unroll
    for (int i=0;i<8;i++) acc[i]=0.f;
    for (int k=0;k<ED;k++){
        float w = Wm[k*UN + u];
#pragma unroll
        for (int tt=0; tt<8; tt++) acc[tt] += v[tt*512 + k]*w;
    }
#pragma unroll
    for (int tt=0; tt<8; tt++)
        keys[(size_t)b*TE*UN + (size_t)(tg*8+tt)*UN + u] = acc[tt];
}

// ---------------- decT[t][k][b] = dec[b][t][k] (one-time transpose) ----------------
__global__ void dect_kernel(const float* __restrict__ dec, float* __restrict__ decT)
{
    int t = blockIdx.x; int tid = threadIdx.x; // 256
    __shared__ float tile[32*80];
    for (int o = tid; o < 32*80; o += 256){
        int b = o/80, k = o%80;
        tile[o] = dec[((size_t)b*TD + t)*DD + k];
    }
    __syncthreads();
    for (int o = tid; o < 80*32; o += 256){
        int k = o>>5, b = o&31;
        decT[((size_t)t*DD + k)*B + b] = tile[b*80 + k];
    }
}

// ---------------- grid barrier (all NBLK blocks resident: 85KB LDS -> 1 block/CU) -----
__device__ __forceinline__ void gridbar(unsigned* cnt, unsigned* gen, unsigned& epoch)
{
    __syncthreads();
    if (threadIdx.x == 0){
        epoch++;
        unsigned prev = __hip_atomic_fetch_add(cnt, 1u, __ATOMIC_ACQ_REL, __HIP_MEMORY_SCOPE_AGENT);
        if (prev == (unsigned)(NBLK-1)){
            __hip_atomic_store(cnt, 0u, __ATOMIC_RELAXED, __HIP_MEMORY_SCOPE_AGENT);
            __hip_atomic_store(gen, epoch, __ATOMIC_RELEASE, __HIP_MEMORY_SCOPE_AGENT);
        } else {
            while (__hip_atomic_load(gen, __ATOMIC_RELAXED, __HIP_MEMORY_SCOPE_AGENT) < epoch)
                __builtin_amdgcn_s_sleep(2);
            (void)__hip_atomic_load(gen, __ATOMIC_ACQUIRE, __HIP_MEMORY_SCOPE_AGENT);
        }
    }
    __syncthreads();
}

// ---------------- persistent recurrence kernel ----------------
__global__ __launch_bounds__(NTHR, 2) void persist(
    const float* __restrict__ enc,   // values [B][TE][ED]
    const float* __restrict__ decT,  // [TD][DD][B]
    const float* __restrict__ keys,  // [B][TE][UN]
    const float* __restrict__ W0, const float* __restrict__ U0, const float* __restrict__ b0v,
    const float* __restrict__ W1, const float* __restrict__ U1, const float* __restrict__ b1v,
    const float* __restrict__ Wq, const float* __restrict__ convk, const float* __restrict__ convb,
    const float* __restrict__ Wloc, const float* __restrict__ v_a, const float* __restrict__ b_a,
    float* __restrict__ h0T,   // [2][LS][B]
    float* __restrict__ h1T,   // [2][LS][B]
    float* __restrict__ align_,// [B][TE] cumulative
    float* __restrict__ denomh,// [TD][B]
    float* __restrict__ ctxp,  // [8][ED][B] per-step unnormalized ctx partials
    unsigned* __restrict__ bar,// [64] (cnt at 0, gen at 32)
    float* __restrict__ c_out, float* __restrict__ e_out)
{
    __shared__ __align__(16) float xh[512*16];  // staging  [k_chunk][16 b]
    __shared__ float zp[512*17];                // k-split partials, stride 17 vs bank conflicts
    __shared__ float zr[512];                   // reduced z [32 col][16 b]
    __shared__ float cst0[128], cst1[128];      // LSTM cell state slices (block-owned)
    __shared__ float invd[16];
    __shared__ float pqp[512];
    __shared__ float pq[128];
    __shared__ float aw[96];
    __shared__ float fls[50*FLT];
    __shared__ float epart[128];
    __shared__ float alds[64];
    __shared__ float wtile[32*33];

    const int tid = threadIdx.x;
    const int p   = blockIdx.x;
    // GEMM mapping: XCD-chunked so adjacent-unit blocks share an XCD L2
    const int xcd  = p & 7, slot = p >> 3;
    const int ut   = xcd*16 + (slot>>1);   // 0..127 : 8 units each
    const int bt   = slot & 1;             // batch tile (16 b)
    const int b0   = bt*16;
    const int c    = tid & 31;             // 32 cols = 8 units x 4 gates
    const int ks   = tid >> 5;             // 16-way k split within block
    const int gate = c >> 3, ui = c & 7;
    const int col  = gate*1024 + ut*8 + ui;
    // attention mapping
    const int ab  = p >> 3;                // batch
    const int ach = p & 7;                 // 50-position chunk
    const int t0  = ach*50;

    if (tid < 128){ cst0[tid] = 0.f; cst1[tid] = 0.f; }
    unsigned epoch = 0;
    unsigned* cntp = bar;
    unsigned* genp = bar + 32;
    __syncthreads();

    for (int t = 0; t < TD; t++){
        //======================= phase 1: z0 -> h0 =======================
        if (tid < 16) invd[tid] = (t==0) ? 0.f : 1.f/denomh[(size_t)(t-1)*B + b0 + tid];
        __syncthreads();
        {
            float acc[16];
#pragma unroll
            for (int i=0;i<16;i++) acc[i]=0.f;
            const float* wA = W0 + col;
            const float* wB = U0 + col;
            for (int k0 = 0; k0 < 1616; k0 += 404){
                for (int i = tid; i < 404*16; i += NTHR){
                    int kk = i >> 4, bb = i & 15;
                    int k = k0 + kk;
                    float v;
                    if (k < DD) v = decT[((size_t)t*DD + k)*B + b0 + bb];
                    else if (k < DD+ED){
                        if (t == 0) v = 0.f;
                        else {
                            int d = k - DD;
                            float s8 = 0.f;
#pragma unroll
                            for (int ch=0; ch<8; ch++) s8 += ctxp[((size_t)ch*ED + d)*B + b0 + bb];
                            v = s8 * invd[bb];
                        }
                    } else v = h0T[(size_t)((t&1)^1)*LS*B + (size_t)(k-(DD+ED))*B + b0 + bb];
                    xh[i] = v;
                }
                __syncthreads();
                for (int kk = ks; kk < 404; kk += 16){
                    int k = k0 + kk;
                    float w = (k < DD+ED) ? wA[(size_t)k*G4] : wB[(size_t)(k-(DD+ED))*G4];
                    const float4* xr = (const float4*)&xh[kk*16];
#pragma unroll
                    for (int i=0;i<4;i++){
                        float4 x4 = xr[i];
                        acc[4*i+0] += x4.x*w; acc[4*i+1] += x4.y*w;
                        acc[4*i+2] += x4.z*w; acc[4*i+3] += x4.w*w;
                    }
                }
                __syncthreads();
            }
#pragma unroll
            for (int bb=0; bb<16; bb++) zp[(ks*32 + c)*17 + bb] = acc[bb];
        }
        __syncthreads();
        {
            int co = tid >> 4, bb = tid & 15;
            float z = 0.f;
#pragma unroll
            for (int q=0;q<16;q++) z += zp[(q*32 + co)*17 + bb];
            zr[tid] = z + b0v[(co>>3)*1024 + ut*8 + (co&7)];
        }
        __syncthreads();
        if (tid < 128){
            int uio = tid >> 4, bb = tid & 15;
            float zi = zr[(0*8+uio)*16 + bb];
            float zf = zr[(1*8+uio)*16 + bb];
            float zg = zr[(2*8+uio)*16 + bb];
            float zo = zr[(3*8+uio)*16 + bb];
            float cn = fsig(zf)*cst0[tid] + fsig(zi)*ftanh(zg);
            float hn = fsig(zo)*ftanh(cn);
            cst0[tid] = cn;
            h0T[(size_t)(t&1)*LS*B + (size_t)(ut*8+uio)*B + b0 + bb] = hn;
        }
        // c_out writer: blocks 0..15 transpose+write step t-1 context (unnormalized)
        if (p < 16 && t > 0){
            int d0 = p*32;
            for (int o = tid; o < 1024; o += NTHR){
                int dd = o>>5, bb = o&31;
                float s8 = 0.f;
#pragma unroll
                for (int ch=0; ch<8; ch++) s8 += ctxp[((size_t)ch*ED + d0+dd)*B + bb];
                wtile[dd*33+bb] = s8;
            }
            __syncthreads();
            for (int o = tid; o < 1024; o += NTHR){
                int bb = o>>5, dd = o&31;
                c_out[((size_t)bb*TD + (t-1))*ED + d0+dd] = wtile[dd*33+bb];
            }
        }
        gridbar(cntp, genp, epoch);

        //======================= phase 2: z1 -> h1 =======================
        // side task: fold a_{t-1} into cumulative alignment (each block owns its 50-chunk)
        if (t > 0 && tid < 50){
            float idn = 1.f / denomh[(size_t)(t-1)*B + ab];
            align_[(size_t)ab*TE + t0 + tid] +=
                e_out[((size_t)ab*TD + (t-1))*TE + t0 + tid] * idn;
        }
        {
            float acc[16];
#pragma unroll
            for (int i=0;i<16;i++) acc[i]=0.f;
            const float* wA = W1 + col;
            const float* wB = U1 + col;
            for (int k0 = 0; k0 < 2048; k0 += 512){
                for (int i = tid; i < 512*16; i += NTHR){
                    int kk = i >> 4, bb = i & 15;
                    int k = k0 + kk;
                    xh[i] = (k < LS) ? h0T[(size_t)(t&1)*LS*B + (size_t)k*B + b0 + bb]
                                     : h1T[(size_t)((t&1)^1)*LS*B + (size_t)(k-LS)*B + b0 + bb];
                }
                __syncthreads();
                for (int kk = ks; kk < 512; kk += 16){
                    int k = k0 + kk;
                    float w = (k < LS) ? wA[(size_t)k*G4] : wB[(size_t)(k-LS)*G4];
                    const float4* xr = (const float4*)&xh[kk*16];
#pragma unroll
                    for (int i=0;i<4;i++){
                        float4 x4 = xr[i];
                        acc[4*i+0] += x4.x*w; acc[4*i+1] += x4.y*w;
                        acc[4*i+2] += x4.z*w; acc[4*i+3] += x4.w*w;
                    }
                }
                __syncthreads();
            }
#pragma unroll
            for (int bb=0; bb<16; bb++) zp[(ks*32 + c)*17 + bb] = acc[bb];
        }
        __syncthreads();
        {
            int co = tid >> 4, bb = tid & 15;
            float z = 0.f;
#pragma unroll
            for (int q=0;q<16;q++) z += zp[(q*32 + co)*17 + bb];
            zr[tid] = z + b1v[(co>>3)*1024 + ut*8 + (co&7)];
        }
        __syncthreads();
        if (tid < 128){
            int uio = tid >> 4, bb = tid & 15;
            float zi = zr[(0*8+uio)*16 + bb];
            float zf = zr[(1*8+uio)*16 + bb];
            float zg = zr[(2*8+uio)*16 + bb];
            float zo = zr[(3*8+uio)*16 + bb];
            float cn = fsig(zf)*cst1[tid] + fsig(zi)*ftanh(zg);
            float hn = fsig(zo)*ftanh(cn);
            cst1[tid] = cn;
            h1T[(size_t)(t&1)*LS*B + (size_t)(ut*8+uio)*B + b0 + bb] = hn;
        }
        gridbar(cntp, genp, epoch);

        //======================= phase 3: attention =======================
        {
            const float* h1r = h1T + (size_t)(t&1)*LS*B;
            int u = tid & 127, kq = tid >> 7;
            float s = 0.f;
            for (int k = kq*256; k < kq*256+256; k++)
                s += h1r[(size_t)k*B + ab] * Wq[(size_t)k*UN + u];
            pqp[kq*128 + u] = s;
        }
        if (tid >= 128 && tid < 208){
            int j = tid - 128;
            int pp = t0 + j - 15;
            aw[j] = (pp >= 0 && pp < TE) ? align_[(size_t)ab*TE + pp] : 0.f;
        }
        __syncthreads();
        if (tid < 128) pq[tid] = pqp[tid] + pqp[128+tid] + pqp[256+tid] + pqp[384+tid] + b_a[tid];
        __syncthreads();
        for (int o = tid; o < 50*FLT; o += NTHR){
            int pos = o >> 5, fl = o & 31;
            float s = convb[fl];
#pragma unroll
            for (int k=0;k<KW;k++) s += aw[pos+k]*convk[k*FLT+fl];
            fls[o] = s;
        }
        __syncthreads();
        {
            const float* kb = keys + ((size_t)ab*TE + t0)*UN;
            for (int o = tid; o < 50*UN; o += NTHR){
                int pos = o >> 7, u = o & 127;
                float loc = 0.f;
                const float* fr = &fls[pos*FLT];
#pragma unroll
                for (int fl=0; fl<FLT; fl++) loc += fr[fl]*Wloc[fl*UN+u];
                float x = kb[(size_t)pos*UN + u] + pq[u] + loc;   // b_a folded into pq
                float val = v_a[u]*ftanh(x);
                val += __shfl_down(val, 32, 64);
                val += __shfl_down(val, 16, 64);
                val += __shfl_down(val,  8, 64);
                val += __shfl_down(val,  4, 64);
                val += __shfl_down(val,  2, 64);
                val += __shfl_down(val,  1, 64);
                if ((tid & 63) == 0) epart[o >> 6] = val;
            }
        }
        __syncthreads();
        if (tid < 50){
            float e = epart[tid*2] + epart[tid*2+1];
            float ex = __expf(e);   // |e| small: max-free softmax safe
            e_out[((size_t)ab*TD + t)*TE + t0 + tid] = ex;   // unnormalized; final pass divides
            alds[tid] = ex;
        }
        __syncthreads();
        if (tid == 0){
            float s = 0.f;
#pragma unroll
            for (int i=0;i<50;i++) s += alds[i];
            atomicAdd(&denomh[(size_t)t*B + ab], s);
        }
        {
            const float* vb = enc + ((size_t)ab*TE + t0)*ED;
            float a2 = 0.f;
#pragma unroll 10
            for (int pp=0; pp<50; pp++) a2 += alds[pp]*vb[(size_t)pp*ED + tid];
            ctxp[((size_t)ach*ED + tid)*B + ab] = a2;   // unnormalized partial
        }
        gridbar(cntp, genp, epoch);
    }
}

// ---------------- final normalization ----------------
__global__ void norm_e_kernel(const float* __restrict__ denomh, float* __restrict__ e_out)
{
    size_t idx = (size_t)blockIdx.x*512 + threadIdx.x;
    int b = (int)(idx / ((size_t)TD*TE));
    int r = (int)(idx % ((size_t)TD*TE));
    int t = r / TE;
    e_out[idx] = e_out[idx] / denomh[(size_t)t*B + b];
}

__global__ void norm_c_kernel(const float* __restrict__ denomh, const float* __restrict__ ctxp,
                              float* __restrict__ c_out)
{
    size_t idx = (size_t)blockIdx.x*512 + threadIdx.x;
    int b = (int)(idx / ((size_t)TD*ED));
    int r = (int)(idx % ((size_t)TD*ED));
    int t = r / ED;
    int d = r % ED;
    float v;
    if (t == TD-1){
        v = 0.f;
#pragma unroll
        for (int ch=0; ch<8; ch++) v += ctxp[((size_t)ch*ED + d)*B + b];
    } else v = c_out[idx];
    c_out[idx] = v / denomh[(size_t)t*B + b];
}

extern "C" void kernel_launch(void* const* d_in, const int* in_sizes, int n_in,
                              void* d_out, int out_size, void* d_ws, size_t ws_size,
                              hipStream_t stream)
{
    const float* enc   = (const float*)d_in[0];
    const float* dec   = (const float*)d_in[1];
    const float* Wm    = (const float*)d_in[2];
    const float* Wq    = (const float*)d_in[3];
    const float* convk = (const float*)d_in[4];
    const float* convb = (const float*)d_in[5];
    const float* Wloc  = (const float*)d_in[6];
    const float* v_a   = (const float*)d_in[7];
    const float* b_a   = (const float*)d_in[8];
    const float* W0    = (const float*)d_in[9];
    const float* U0    = (const float*)d_in[10];
    const float* b0    = (const float*)d_in[11];
    const float* W1    = (const float*)d_in[12];
    const float* U1    = (const float*)d_in[13];
    const float* b1    = (const float*)d_in[14];

    float* out   = (float*)d_out;
    float* c_out = out;                                  // [B, TD, ED]
    float* e_out = out + (size_t)B*TD*ED;                // [B, TD, TE]

    float* ws     = (float*)d_ws;
    float* h0T    = ws;                                  // 2*LS*B
    float* h1T    = h0T + (size_t)2*LS*B;                // 2*LS*B
    float* align_ = h1T + (size_t)2*LS*B;                // B*TE
    float* denomh = align_ + (size_t)B*TE;               // TD*B
    unsigned* bar = (unsigned*)(denomh + (size_t)TD*B);  // 64 uints (256 B)
    float* keys   = denomh + (size_t)TD*B + 64;          // B*TE*UN
    float* decT   = keys + (size_t)B*TE*UN;              // TD*DD*B
    float* ctxp   = decT + (size_t)TD*DD*B;              // 8*ED*B

    // zero recurrent state + alignment + denominators + barrier (ws poisoned per call)
    hipMemsetAsync(ws, 0,
        ((size_t)(4*LS*B + B*TE + TD*B) + 64)*sizeof(float), stream);

    keys_kernel<<<dim3(B,50), 128, 0, stream>>>(enc, Wm, keys);
    dect_kernel<<<TD, 256, 0, stream>>>(dec, decT);

    persist<<<NBLK, NTHR, 0, stream>>>(enc, decT, keys,
                                       W0, U0, b0, W1, U1, b1,
                                       Wq, convk, convb, Wloc, v_a, b_a,
                                       h0T, h1T, align_, denomh, ctxp, bar,
                                       c_out, e_out);

    norm_e_kernel<<<(B*TD*TE)/512, 512, 0, stream>>>(denomh, e_out);
    norm_c_kernel<<<(B*TD*ED)/512, 512, 0, stream>>>(denomh, ctxp, c_out);
}

// Round 2
// 173432.812 us; speedup vs baseline: 1.0194x; 1.0194x over previous
//
#include <hip/hip_runtime.h>
#include <math.h>
#include <stddef.h>

#define B   32
#define TE  400
#define TD  800
#define ED  512
#define DD  80
#define LS  1024
#define G4  4096
#define UN  128
#define FLT 32
#define KW  31

#define NBLK 256
#define NTHR 512

__device__ __forceinline__ float fsig(float x){ return 1.f/(1.f+__expf(-x)); }
__device__ __forceinline__ float ftanh(float x){ return 1.f - 2.f/(__expf(2.f*x)+1.f); }

// ---------------- keys = values @ Wm : [B, TE, UN] (one-time) ----------------
__global__ void keys_kernel(const float* __restrict__ values, const float* __restrict__ Wm,
                            float* __restrict__ keys)
{
    int b  = blockIdx.x;
    int tg = blockIdx.y;
    int tid = threadIdx.x;    // 128
    __shared__ __align__(16) float v[8*512];
    const float* vb = values + (size_t)b*TE*ED + (size_t)tg*8*ED;
    for (int i = tid; i < 8*512; i += 128) v[i] = vb[i];
    __syncthreads();
    int u = tid;
    float acc[8];
#pragma unroll
    for (int i=0;i<8;i++) acc[i]=0.f;
    for (int k=0;k<ED;k++){
        float w = Wm[k*UN + u];
#pragma unroll
        for (int tt=0; tt<8; tt++) acc[tt] += v[tt*512 + k]*w;
    }
#pragma unroll
    for (int tt=0; tt<8; tt++)
        keys[(size_t)b*TE*UN + (size_t)(tg*8+tt)*UN + u] = acc[tt];
}

// ---------------- decT[t][k][b] = dec[b][t][k] (one-time transpose) ----------------
__global__ void dect_kernel(const float* __restrict__ dec, float* __restrict__ decT)
{
    int t = blockIdx.x; int tid = threadIdx.x; // 256
    __shared__ float tile[32*80];
    for (int o = tid; o < 32*80; o += 256){
        int b = o/80, k = o%80;
        tile[o] = dec[((size_t)b*TD + t)*DD + k];
    }
    __syncthreads();
    for (int o = tid; o < 80*32; o += 256){
        int k = o>>5, b = o&31;
        decT[((size_t)t*DD + k)*B + b] = tile[b*80 + k];
    }
}

// ---------------- grid barrier (all 256 blocks resident, 1 block/CU) ----------------
__device__ __forceinline__ void gridbar(unsigned* cnt, unsigned* gen, unsigned& epoch)
{
    __syncthreads();
    if (threadIdx.x == 0){
        epoch++;
        unsigned prev = __hip_atomic_fetch_add(cnt, 1u, __ATOMIC_ACQ_REL, __HIP_MEMORY_SCOPE_AGENT);
        if (prev == (unsigned)(NBLK-1)){
            __hip_atomic_store(cnt, 0u, __ATOMIC_RELAXED, __HIP_MEMORY_SCOPE_AGENT);
            __hip_atomic_store(gen, epoch, __ATOMIC_RELEASE, __HIP_MEMORY_SCOPE_AGENT);
        } else {
            while (__hip_atomic_load(gen, __ATOMIC_RELAXED, __HIP_MEMORY_SCOPE_AGENT) < epoch)
                __builtin_amdgcn_s_sleep(2);
            (void)__hip_atomic_load(gen, __ATOMIC_ACQUIRE, __HIP_MEMORY_SCOPE_AGENT);
        }
    }
    __syncthreads();
}

// FMA over one staged k-chunk: thread's k = ksub + 128*(JB+jj), kk = ksub + 128*jj
#define FMA_CHUNK(WR, JB, JC)                                                 \
  {                                                                           \
    _Pragma("unroll")                                                         \
    for (int jj = 0; jj < (JC); jj++){                                        \
      const float* xr = &xh[(ksub + 128*jj)*20];                              \
      float4 x0 = *(const float4*)(xr+0);                                     \
      float4 x1 = *(const float4*)(xr+4);                                     \
      float4 x2 = *(const float4*)(xr+8);                                     \
      float4 x3 = *(const float4*)(xr+12);                                    \
      _Pragma("unroll")                                                       \
      for (int g = 0; g < 4; g++){                                            \
        float w = WR[g][(JB)+jj];                                             \
        acc[g][0]  += w*x0.x;  acc[g][1]  += w*x0.y;                          \
        acc[g][2]  += w*x0.z;  acc[g][3]  += w*x0.w;                          \
        acc[g][4]  += w*x1.x;  acc[g][5]  += w*x1.y;                          \
        acc[g][6]  += w*x1.z;  acc[g][7]  += w*x1.w;                          \
        acc[g][8]  += w*x2.x;  acc[g][9]  += w*x2.y;                          \
        acc[g][10] += w*x2.z;  acc[g][11] += w*x2.w;                          \
        acc[g][12] += w*x3.x;  acc[g][13] += w*x3.y;                          \
        acc[g][14] += w*x3.z;  acc[g][15] += w*x3.w;                          \
      }                                                                       \
    }                                                                         \
  }

// stage x chunk CI (512 k x 16 b) for phase 1: x = [dec ; ctx ; h0_prev ; 0-pad]
#define STAGE_PH1(CI)                                                         \
  {                                                                           \
    _Pragma("unroll")                                                         \
    for (int q = 0; q < 4; q++){                                              \
      int f = tid + q*512;                                                    \
      int kk = f >> 2;                                                        \
      int bq = f & 3;                                                         \
      int k = (CI)*512 + kk;                                                  \
      int b = bh*16 + bq*4;                                                   \
      float4 v;                                                               \
      if (k < 80){                                                            \
        v = *(const float4*)&decT[((size_t)t*80 + k)*32 + b];                 \
      } else if (k < 592){                                                    \
        if (t == 0){ v.x=0.f; v.y=0.f; v.z=0.f; v.w=0.f; }                    \
        else {                                                                \
          v = *(const float4*)&ctxacc[(size_t)(par^1)*16384 + (size_t)(k-80)*32 + b]; \
          v.x *= invd[b]; v.y *= invd[b+1]; v.z *= invd[b+2]; v.w *= invd[b+3]; \
        }                                                                     \
      } else if (k < 1616){                                                   \
        v = *(const float4*)&h0T[(size_t)(par^1)*32768 + (size_t)(k-592)*32 + b]; \
      } else { v.x=0.f; v.y=0.f; v.z=0.f; v.w=0.f; }                          \
      *(float4*)&xh[kk*20 + bq*4] = v;                                        \
    }                                                                         \
  }

// stage x chunk CI for phase 2: x = [h0_cur ; h1_prev]
#define STAGE_PH2(CI)                                                         \
  {                                                                           \
    _Pragma("unroll")                                                         \
    for (int q = 0; q < 4; q++){                                              \
      int f = tid + q*512;                                                    \
      int kk = f >> 2;                                                        \
      int bq = f & 3;                                                         \
      int k = (CI)*512 + kk;                                                  \
      int b = bh*16 + bq*4;                                                   \
      float4 v;                                                               \
      if (k < 1024) v = *(const float4*)&h0T[(size_t)par*32768 + (size_t)k*32 + b]; \
      else          v = *(const float4*)&h1T[(size_t)(par^1)*32768 + (size_t)(k-1024)*32 + b]; \
      *(float4*)&xh[kk*20 + bq*4] = v;                                        \
    }                                                                         \
  }

// in-register k-split reduction: butterfly over lane bits 2..5 with payload halving,
// then tiny LDS combine of the 8 per-wave partials into zfin[:, BH*16..]
#define REDUCE_PASS(BH)                                                       \
  {                                                                           \
    float t32[32];                                                            \
    { bool hi = (lane & 4) != 0;                                              \
      _Pragma("unroll")                                                       \
      for (int i = 0; i < 32; i++){                                           \
        int gs = i >> 4;                                                      \
        int b  = i & 15;                                                      \
        float keep = hi ? acc[2+gs][b] : acc[gs][b];                          \
        float give = hi ? acc[gs][b]   : acc[2+gs][b];                        \
        t32[i] = keep + __shfl_xor(give, 4, 64);                              \
      } }                                                                     \
    float t16[16];                                                            \
    { bool hi = (lane & 8) != 0;                                              \
      _Pragma("unroll")                                                       \
      for (int i = 0; i < 16; i++){                                           \
        float keep = hi ? t32[16+i] : t32[i];                                 \
        float give = hi ? t32[i]    : t32[16+i];                              \
        t16[i] = keep + __shfl_xor(give, 8, 64);                              \
      } }                                                                     \
    float t8[8];                                                              \
    { bool hi = (lane & 16) != 0;                                             \
      _Pragma("unroll")                                                       \
      for (int i = 0; i < 8; i++){                                            \
        float keep = hi ? t16[8+i] : t16[i];                                  \
        float give = hi ? t16[i]   : t16[8+i];                                \
        t8[i] = keep + __shfl_xor(give, 16, 64);                              \
      } }                                                                     \
    float t4[4];                                                              \
    { bool hi = (lane & 32) != 0;                                             \
      _Pragma("unroll")                                                       \
      for (int i = 0; i < 4; i++){                                            \
        float keep = hi ? t8[4+i] : t8[i];                                    \
        float give = hi ? t8[i]   : t8[4+i];                                  \
        t4[i] = keep + __shfl_xor(give, 32, 64);                              \
      } }                                                                     \
    int gg  = ((lane>>2)&1)*2 + ((lane>>3)&1);                                \
    int bb0 = ((lane>>4)&1)*8 + ((lane>>5)&1)*4;                              \
    int wv  = tid >> 6;                                                       \
    float* zp2 = xh;                                                          \
    *(float4*)&zp2[wv*256 + gg*64 + ui*16 + bb0] = make_float4(t4[0],t4[1],t4[2],t4[3]); \
    __syncthreads();                                                          \
    if (tid < 256){                                                           \
      int cc = tid >> 4;                                                      \
      int b  = tid & 15;                                                      \
      float s = 0.f;                                                          \
      _Pragma("unroll")                                                       \
      for (int w8 = 0; w8 < 8; w8++) s += zp2[w8*256 + cc*16 + b];            \
      zfin[cc*33 + (BH)*16 + b] = s;                                          \
    }                                                                         \
    __syncthreads();                                                          \
  }

// ---------------- persistent recurrence kernel (weights in registers) ----------------
__global__ __launch_bounds__(NTHR, 2) void persist(
    const float* __restrict__ enc,   // values [B][TE][ED]
    const float* __restrict__ decT,  // [TD][80][32]
    const float* __restrict__ keys,  // [B][TE][UN]
    const float* __restrict__ W0, const float* __restrict__ U0, const float* __restrict__ b0v,
    const float* __restrict__ W1, const float* __restrict__ U1, const float* __restrict__ b1v,
    const float* __restrict__ Wq, const float* __restrict__ convk, const float* __restrict__ convb,
    const float* __restrict__ Wloc, const float* __restrict__ v_a, const float* __restrict__ b_a,
    float* __restrict__ h0T,   // [2][1024][32]
    float* __restrict__ h1T,   // [2][1024][32]
    float* __restrict__ align_,// [B][TE] cumulative
    float* __restrict__ denomh,// [TD][B]
    float* __restrict__ ctxp_unused,
    float* __restrict__ ctxacc,// [2][512][32] unnormalized ctx accumulator (atomic)
    unsigned* __restrict__ bar,// cnt at 0, gen at 32
    float* __restrict__ c_out, float* __restrict__ e_out)
{
    __shared__ __align__(16) float xh[512*20];   // 40KB staging (stride 20) / zp2 overlay
    __shared__ float zfin[16*33];                // z [16 cols][32 b] (+pad)
    __shared__ float cst0[128], cst1[128];       // cell state [4 units][32 b]
    __shared__ float invd[32];
    __shared__ float pqp[512];
    __shared__ float pq[128];
    __shared__ float aw[96];
    __shared__ float fls[50*FLT];
    __shared__ float epart[128];
    __shared__ float alds[64];

    const int tid  = threadIdx.x;
    const int p    = blockIdx.x;
    const int lane = tid & 63;
    const int ui   = tid & 3;        // unit within block
    const int ksub = tid >> 2;       // 0..127 k-split
    const int u0   = p * 4;          // block owns units u0..u0+3
    // attention mapping
    const int ab  = p >> 3;          // batch
    const int ach = p & 7;           // 50-position chunk
    const int t0a = ach*50;

    // ---- one-time: load this thread's weight slices into registers ----
    // col(g) = g*1024 + u0 + ui ; k = ksub + 128*j
    float w0r[4][13];
#pragma unroll
    for (int j = 0; j < 13; j++){
        int k = ksub + 128*j;
#pragma unroll
        for (int g = 0; g < 4; g++){
            int col = g*1024 + u0 + ui;
            float w;
            if (k < 592)       w = W0[(size_t)k*G4 + col];
            else if (k < 1616) w = U0[(size_t)(k-592)*G4 + col];
            else               w = 0.f;
            w0r[g][j] = w;
        }
    }
    float w1r[4][16];
#pragma unroll
    for (int j = 0; j < 16; j++){
        int k = ksub + 128*j;
#pragma unroll
        for (int g = 0; g < 4; g++){
            int col = g*1024 + u0 + ui;
            w1r[g][j] = (k < 1024) ? W1[(size_t)k*G4 + col]
                                   : U1[(size_t)(k-1024)*G4 + col];
        }
    }

    if (tid < 128){ cst0[tid] = 0.f; cst1[tid] = 0.f; }
    unsigned epoch = 0;
    unsigned* cntp = bar;
    unsigned* genp = bar + 32;
    __syncthreads();

    for (int t = 0; t < TD; t++){
        const int par = t & 1;
        //======================= phase 1: z0 -> h0 =======================
        if (tid < 32) invd[tid] = (t>0) ? 1.f/denomh[(size_t)(t-1)*32 + tid] : 0.f;
        __syncthreads();
        for (int bh = 0; bh < 2; bh++){
            float acc[4][16];
#pragma unroll
            for (int g=0; g<4; g++)
#pragma unroll
                for (int i=0; i<16; i++) acc[g][i] = 0.f;
            STAGE_PH1(0) __syncthreads(); FMA_CHUNK(w0r, 0, 4) __syncthreads();
            STAGE_PH1(1) __syncthreads(); FMA_CHUNK(w0r, 4, 4) __syncthreads();
            STAGE_PH1(2) __syncthreads(); FMA_CHUNK(w0r, 8, 4) __syncthreads();
            STAGE_PH1(3) __syncthreads(); FMA_CHUNK(w0r, 12, 1) __syncthreads();
            REDUCE_PASS(bh)
        }
        if (tid < 128){
            int u = tid >> 5, b = tid & 31;
            float zi = zfin[(0*4+u)*33 + b] + b0v[0*1024 + u0 + u];
            float zf = zfin[(1*4+u)*33 + b] + b0v[1*1024 + u0 + u];
            float zg = zfin[(2*4+u)*33 + b] + b0v[2*1024 + u0 + u];
            float zo = zfin[(3*4+u)*33 + b] + b0v[3*1024 + u0 + u];
            float cn = fsig(zf)*cst0[tid] + fsig(zi)*ftanh(zg);
            float hn = fsig(zo)*ftanh(cn);
            cst0[tid] = cn;
            h0T[(size_t)par*32768 + (size_t)(u0+u)*32 + b] = hn;
        }
        gridbar(cntp, genp, epoch);

        //======================= phase 2: z1 -> h1 =======================
        if (t > 0){
            // fold a_{t-1} into cumulative alignment (block owns its 50-chunk)
            if (tid < 50){
                float idn = 1.f / denomh[(size_t)(t-1)*32 + ab];
                align_[(size_t)ab*TE + t0a + tid] +=
                    e_out[((size_t)ab*TD + (t-1))*TE + t0a + tid] * idn;
            }
            // write normalized c_out row t-1 and zero the consumed ctxacc buffer
            if (p < 32){
                float idn = 1.f / denomh[(size_t)(t-1)*32 + p];
                int d = tid;
                size_t ci = (size_t)(par^1)*16384 + (size_t)d*32 + p;
                float v = ctxacc[ci];
                c_out[((size_t)p*TD + (t-1))*ED + d] = v * idn;
                ctxacc[ci] = 0.f;
            }
        }
        for (int bh = 0; bh < 2; bh++){
            float acc[4][16];
#pragma unroll
            for (int g=0; g<4; g++)
#pragma unroll
                for (int i=0; i<16; i++) acc[g][i] = 0.f;
            STAGE_PH2(0) __syncthreads(); FMA_CHUNK(w1r, 0, 4) __syncthreads();
            STAGE_PH2(1) __syncthreads(); FMA_CHUNK(w1r, 4, 4) __syncthreads();
            STAGE_PH2(2) __syncthreads(); FMA_CHUNK(w1r, 8, 4) __syncthreads();
            STAGE_PH2(3) __syncthreads(); FMA_CHUNK(w1r, 12, 4) __syncthreads();
            REDUCE_PASS(bh)
        }
        if (tid < 128){
            int u = tid >> 5, b = tid & 31;
            float zi = zfin[(0*4+u)*33 + b] + b1v[0*1024 + u0 + u];
            float zf = zfin[(1*4+u)*33 + b] + b1v[1*1024 + u0 + u];
            float zg = zfin[(2*4+u)*33 + b] + b1v[2*1024 + u0 + u];
            float zo = zfin[(3*4+u)*33 + b] + b1v[3*1024 + u0 + u];
            float cn = fsig(zf)*cst1[tid] + fsig(zi)*ftanh(zg);
            float hn = fsig(zo)*ftanh(cn);
            cst1[tid] = cn;
            h1T[(size_t)par*32768 + (size_t)(u0+u)*32 + b] = hn;
        }
        gridbar(cntp, genp, epoch);

        //======================= phase 3: attention =======================
        {
            const float* h1r = h1T + (size_t)par*32768;
            int u = tid & 127, kq = tid >> 7;
            float s = 0.f;
            for (int k = kq*256; k < kq*256+256; k++)
                s += h1r[(size_t)k*32 + ab] * Wq[(size_t)k*UN + u];
            pqp[kq*128 + u] = s;
        }
        if (tid >= 128 && tid < 208){
            int j = tid - 128;
            int pp = t0a + j - 15;
            aw[j] = (pp >= 0 && pp < TE) ? align_[(size_t)ab*TE + pp] : 0.f;
        }
        __syncthreads();
        if (tid < 128) pq[tid] = pqp[tid] + pqp[128+tid] + pqp[256+tid] + pqp[384+tid] + b_a[tid];
        __syncthreads();
        for (int o = tid; o < 50*FLT; o += NTHR){
            int pos = o >> 5, fl = o & 31;
            float s = convb[fl];
#pragma unroll
            for (int k=0;k<KW;k++) s += aw[pos+k]*convk[k*FLT+fl];
            fls[o] = s;
        }
        __syncthreads();
        {
            const float* kb = keys + ((size_t)ab*TE + t0a)*UN;
            for (int o = tid; o < 50*UN; o += NTHR){
                int pos = o >> 7, u = o & 127;
                float loc = 0.f;
                const float* fr = &fls[pos*FLT];
#pragma unroll
                for (int fl=0; fl<FLT; fl++) loc += fr[fl]*Wloc[fl*UN+u];
                float x = kb[(size_t)pos*UN + u] + pq[u] + loc;   // b_a folded into pq
                float val = v_a[u]*ftanh(x);
                val += __shfl_down(val, 32, 64);
                val += __shfl_down(val, 16, 64);
                val += __shfl_down(val,  8, 64);
                val += __shfl_down(val,  4, 64);
                val += __shfl_down(val,  2, 64);
                val += __shfl_down(val,  1, 64);
                if ((tid & 63) == 0) epart[o >> 6] = val;
            }
        }
        __syncthreads();
        if (tid < 50){
            float e = epart[tid*2] + epart[tid*2+1];
            float ex = __expf(e);   // |e| small: max-free softmax safe
            e_out[((size_t)ab*TD + t)*TE + t0a + tid] = ex;   // unnormalized; final pass divides
            alds[tid] = ex;
        }
        __syncthreads();
        if (tid == 0){
            float s = 0.f;
#pragma unroll
            for (int i=0;i<50;i++) s += alds[i];
            atomicAdd(&denomh[(size_t)t*32 + ab], s);
        }
        {
            const float* vb = enc + ((size_t)ab*TE + t0a)*ED;
            float a2 = 0.f;
#pragma unroll 10
            for (int pp=0; pp<50; pp++) a2 += alds[pp]*vb[(size_t)pp*ED + tid];
            atomicAdd(&ctxacc[(size_t)par*16384 + (size_t)tid*32 + ab], a2);
        }
        gridbar(cntp, genp, epoch);
    }
}

// ---------------- final normalization ----------------
__global__ void norm_e_kernel(const float* __restrict__ denomh, float* __restrict__ e_out)
{
    size_t idx = (size_t)blockIdx.x*512 + threadIdx.x;
    int b = (int)(idx / ((size_t)TD*TE));
    int r = (int)(idx % ((size_t)TD*TE));
    int t = r / TE;
    e_out[idx] = e_out[idx] / denomh[(size_t)t*B + b];
}

__global__ void norm_c_last(const float* __restrict__ denomh, const float* __restrict__ ctxacc1,
                            float* __restrict__ c_out)
{
    int b = blockIdx.x; int d = threadIdx.x;   // 32 blocks x 512
    c_out[((size_t)b*TD + (TD-1))*ED + d] =
        ctxacc1[(size_t)d*32 + b] / denomh[(size_t)(TD-1)*B + b];
}

extern "C" void kernel_launch(void* const* d_in, const int* in_sizes, int n_in,
                              void* d_out, int out_size, void* d_ws, size_t ws_size,
                              hipStream_t stream)
{
    const float* enc   = (const float*)d_in[0];
    const float* dec   = (const float*)d_in[1];
    const float* Wm    = (const float*)d_in[2];
    const float* Wq    = (const float*)d_in[3];
    const float* convk = (const float*)d_in[4];
    const float* convb = (const float*)d_in[5];
    const float* Wloc  = (const float*)d_in[6];
    const float* v_a   = (const float*)d_in[7];
    const float* b_a   = (const float*)d_in[8];
    const float* W0    = (const float*)d_in[9];
    const float* U0    = (const float*)d_in[10];
    const float* b0    = (const float*)d_in[11];
    const float* W1    = (const float*)d_in[12];
    const float* U1    = (const float*)d_in[13];
    const float* b1    = (const float*)d_in[14];

    float* out   = (float*)d_out;
    float* c_out = out;                                  // [B, TD, ED]
    float* e_out = out + (size_t)B*TD*ED;                // [B, TD, TE]

    float* ws     = (float*)d_ws;
    float* h0T    = ws;                                  // 2*1024*32 = 65536
    float* h1T    = h0T + 65536;                         // 65536
    float* align_ = h1T + 65536;                         // B*TE = 12800
    float* denomh = align_ + 12800;                      // TD*B = 25600
    float* ctxacc = denomh + 25600;                      // 2*512*32 = 32768
    unsigned* bar = (unsigned*)(ctxacc + 32768);         // 64 uints
    float* keys   = (float*)(bar + 64);                  // B*TE*UN = 1638400
    float* decT   = keys + (size_t)B*TE*UN;              // TD*80*32 = 2048000

    // zero recurrent state + alignment + denominators + ctxacc + barrier
    hipMemsetAsync(ws, 0,
        (size_t)(65536 + 65536 + 12800 + 25600 + 32768)*sizeof(float) + 64*sizeof(unsigned),
        stream);

    keys_kernel<<<dim3(B,50), 128, 0, stream>>>(enc, Wm, keys);
    dect_kernel<<<TD, 256, 0, stream>>>(dec, decT);

    persist<<<NBLK, NTHR, 0, stream>>>(enc, decT, keys,
                                       W0, U0, b0, W1, U1, b1,
                                       Wq, convk, convb, Wloc, v_a, b_a,
                                       h0T, h1T, align_, denomh, nullptr, ctxacc, bar,
                                       c_out, e_out);

    norm_e_kernel<<<(B*TD*TE)/512, 512, 0, stream>>>(denomh, e_out);
    norm_c_last<<<32, 512, 0, stream>>>(denomh, ctxacc + 16384, c_out);
}